// Round 1
// baseline (1218.253 us; speedup 1.0000x reference)
//
#include <hip/hip_runtime.h>
#include <hip/hip_bf16.h>
#include <stdint.h>

#define B_ 32
#define S_ 4096
#define D_ 1280
#define R_ 64
#define E_ 8
#define TS 64           // S-rows per block
#define BK 128          // K-chunk (d) for GEMM1
#define LDP 136         // padded LDS row stride in shorts (128 + 8, keeps 16B align)

typedef __attribute__((ext_vector_type(8))) short bf16x8;
typedef __attribute__((ext_vector_type(4))) float f32x4;
typedef __attribute__((ext_vector_type(4))) unsigned short u16x4;

__device__ __forceinline__ unsigned short f2bf(float f) {
    union { float f; uint32_t u; } v; v.f = f;
    uint32_t r = (v.u + 0x7fffu + ((v.u >> 16) & 1u)) >> 16;
    return (unsigned short)r;
}

// Convert all four fp32 weight tensors to raw-bf16 (ushort) in workspace.
__global__ void cvt_all(const float* __restrict__ a, const float* __restrict__ b,
                        const float* __restrict__ c, const float* __restrict__ d,
                        unsigned short* __restrict__ oa, unsigned short* __restrict__ ob,
                        unsigned short* __restrict__ oc, unsigned short* __restrict__ od) {
    int i = blockIdx.x * blockDim.x + threadIdx.x;
    int stride = gridDim.x * blockDim.x;
    for (int k = i; k < E_ * R_ * D_; k += stride) { oa[k] = f2bf(a[k]); ob[k] = f2bf(b[k]); }
    for (int k = i; k < R_ * D_; k += stride)      { oc[k] = f2bf(c[k]); od[k] = f2bf(d[k]); }
}

__global__ __launch_bounds__(256) void moe_lora_fused(
    const float* __restrict__ x,          // [B][S][D]
    const int* __restrict__ label,        // [B]
    const unsigned short* __restrict__ Ae, // bf16 [E][R][D]
    const unsigned short* __restrict__ Be, // bf16 [E][D][R]
    const unsigned short* __restrict__ Ag, // bf16 [R][D]
    const unsigned short* __restrict__ Bg, // bf16 [D][R]
    float* __restrict__ out)              // [B][S][D]
{
    const int tiles_per_b = S_ / TS;               // 64
    const int b  = blockIdx.x / tiles_per_b;
    const int s0 = (blockIdx.x % tiles_per_b) * TS;
    const int tid = threadIdx.x;

    float* outp = out + ((size_t)b * S_ + s0) * (size_t)D_;

    if (b == B_ - 1) {
        // torch loop runs range(B-1): last sample is zero. d_out is poisoned -> must write.
        f32x4 z = {0.f, 0.f, 0.f, 0.f};
        f32x4* o4 = (f32x4*)outp;
        for (int i = tid; i < TS * D_ / 4; i += 256) o4[i] = z;
        return;
    }

    const int lane = tid & 63;
    const int wave = tid >> 6;     // 0..3
    const int llo  = lane & 15;
    const int lhi  = lane >> 4;    // 0..3
    const int lbl  = label[b];

    __shared__ unsigned short xs[TS * LDP];   // 17408 B: x chunk, bf16
    __shared__ unsigned short hs[TS * LDP];   // 17408 B: h tile, bf16

    // ---------------- Phase 1: h[64][128] = x_tile @ Acat^T ----------------
    // B-operand rows: Acat[n][:] = (n<64 ? Ae[lbl][n] : Ag[n-64]); wave owns n-tiles {2w, 2w+1}
    const unsigned short* browp[2];
    #pragma unroll
    for (int j = 0; j < 2; ++j) {
        int n = (2 * wave + j) * 16 + llo;
        browp[j] = (n < R_) ? (Ae + ((size_t)lbl * R_ + n) * D_)
                            : (Ag + (size_t)(n - R_) * D_);
    }

    f32x4 acc1[4][2];
    #pragma unroll
    for (int mt = 0; mt < 4; ++mt)
        #pragma unroll
        for (int j = 0; j < 2; ++j)
            acc1[mt][j] = (f32x4){0.f, 0.f, 0.f, 0.f};

    const float* xp = x + ((size_t)b * S_ + s0) * (size_t)D_;
    const int r0 = tid >> 5;        // 0..7
    const int c4 = (tid & 31) * 4;  // float4 column within chunk

    for (int kc = 0; kc < D_ / BK; ++kc) {
        // stage x chunk [64][128] fp32 -> bf16 LDS
        #pragma unroll
        for (int i = 0; i < 8; ++i) {
            int row = r0 + 8 * i;
            f32x4 v = *(const f32x4*)(xp + (size_t)row * D_ + kc * BK + c4);
            u16x4 h;
            h.x = f2bf(v.x); h.y = f2bf(v.y); h.z = f2bf(v.z); h.w = f2bf(v.w);
            *(u16x4*)&xs[row * LDP + c4] = h;
        }
        __syncthreads();
        #pragma unroll
        for (int ks = 0; ks < BK / 32; ++ks) {
            bf16x8 af[4];
            #pragma unroll
            for (int mt = 0; mt < 4; ++mt)
                af[mt] = *(const bf16x8*)&xs[(mt * 16 + llo) * LDP + ks * 32 + lhi * 8];
            bf16x8 bfr[2];
            #pragma unroll
            for (int j = 0; j < 2; ++j)
                bfr[j] = *(const bf16x8*)(browp[j] + kc * BK + ks * 32 + lhi * 8);
            #pragma unroll
            for (int mt = 0; mt < 4; ++mt)
                #pragma unroll
                for (int j = 0; j < 2; ++j)
                    acc1[mt][j] = __builtin_amdgcn_mfma_f32_16x16x32_bf16(
                        af[mt], bfr[j], acc1[mt][j], 0, 0, 0);
        }
        __syncthreads();
    }

    // write h to LDS as bf16 in A-operand-friendly row-major [m][r]
    #pragma unroll
    for (int mt = 0; mt < 4; ++mt)
        #pragma unroll
        for (int j = 0; j < 2; ++j) {
            int n = (2 * wave + j) * 16 + llo;
            #pragma unroll
            for (int rg = 0; rg < 4; ++rg) {
                int m = mt * 16 + lhi * 4 + rg;
                hs[m * LDP + n] = f2bf(acc1[mt][j][rg]);
            }
        }
    __syncthreads();

    // ---------------- Phase 2: out = 2 * h @ Bcat^T ----------------
    // preload all h A-fragments: [mtile][kstep], 64 VGPRs
    bf16x8 hf[4][4];
    #pragma unroll
    for (int mt = 0; mt < 4; ++mt)
        #pragma unroll
        for (int ks = 0; ks < 4; ++ks)
            hf[mt][ks] = *(const bf16x8*)&hs[(mt * 16 + llo) * LDP + ks * 32 + lhi * 8];

    const unsigned short* BeB = Be + (size_t)lbl * D_ * R_;

    for (int it = 0; it < D_ / 16 / 4; ++it) {   // 20 iters
        int nt = wave + 4 * it;
        int n  = nt * 16 + llo;                  // output column d
        f32x4 acc[4];
        #pragma unroll
        for (int mt = 0; mt < 4; ++mt) acc[mt] = (f32x4){0.f, 0.f, 0.f, 0.f};

        #pragma unroll
        for (int ks = 0; ks < 4; ++ks) {
            // Bcat[n][k]: k<64 from Be[lbl][n][:], k>=64 from Bg[n][:]
            const unsigned short* bp = (ks < 2)
                ? (BeB + (size_t)n * R_ + ks * 32 + lhi * 8)
                : (Bg  + (size_t)n * R_ + (ks - 2) * 32 + lhi * 8);
            bf16x8 bfr = *(const bf16x8*)bp;
            #pragma unroll
            for (int mt = 0; mt < 4; ++mt)
                acc[mt] = __builtin_amdgcn_mfma_f32_16x16x32_bf16(
                    hf[mt][ks], bfr, acc[mt], 0, 0, 0);
        }
        #pragma unroll
        for (int mt = 0; mt < 4; ++mt)
            #pragma unroll
            for (int rg = 0; rg < 4; ++rg) {
                int m = mt * 16 + lhi * 4 + rg;
                outp[(size_t)m * D_ + n] = 2.0f * acc[mt][rg];
            }
    }
}

extern "C" void kernel_launch(void* const* d_in, const int* in_sizes, int n_in,
                              void* d_out, int out_size, void* d_ws, size_t ws_size,
                              hipStream_t stream) {
    const float* x   = (const float*)d_in[0];
    // d_in[1] = weight [B,E] — unused by the reference
    const float* Aef = (const float*)d_in[2];
    const float* Bef = (const float*)d_in[3];
    const float* Agf = (const float*)d_in[4];
    const float* Bgf = (const float*)d_in[5];
    const int* label = (const int*)d_in[6];
    float* out = (float*)d_out;

    unsigned short* Ae = (unsigned short*)d_ws;          // E*R*D = 655360
    unsigned short* Be = Ae + (size_t)E_ * R_ * D_;      // 655360
    unsigned short* Ag = Be + (size_t)E_ * D_ * R_;      // 81920
    unsigned short* Bg = Ag + (size_t)R_ * D_;           // 81920

    cvt_all<<<512, 256, 0, stream>>>(Aef, Bef, Agf, Bgf, Ae, Be, Ag, Bg);

    const int grid = B_ * (S_ / TS);   // 2048
    moe_lora_fused<<<grid, 256, 0, stream>>>(x, label, Ae, Be, Ag, Bg, out);
}